// Round 10
// baseline (2214.522 us; speedup 1.0000x reference)
//
#include <hip/hip_runtime.h>
#include <hip/hip_bf16.h>

// BiLSTM-CRF forward. B=64, L=1024, E=256, H=128 (per dir), C=5, V=32000.
// R22 = R21 resubmitted verbatim (R21 bench was infra failure: GPU
// acquisition timeout; no counters). R20 bodies (bit-exact, absmax 0.0) +
// producer/consumer block-range fusion so GEMM/attn run CONCURRENTLY with
// the lstm recurrence:
//  fused1: blocks [0,32) lstm1, [32,2080) gemm1 (2 tiles per 512-thr block).
//  fused2: blocks [0,64) attn, [64,96) lstm2, [96,2144) gemm2.
//  Gating: per-mblk counter (8 tiles = 8 n-tiles) published with
//  __syncthreads + single-thread __threadfence + device atomicAdd (rocPRIM
//  decoupled-lookback pattern); lstm polls at mblk boundaries (every 2
//  steps) with a tot==4096 fast path; acquire fence on confirm. Tiles
//  ordered alternating from both l-ends so fwd+bwd unblock immediately.
//  Aliasing safe: Y[l] overwrite of X/y1 row l gated on all 8 tiles of
//  mblk=l/2 (confirmed 2 steps ahead of the write); attn fully precedes
//  lstm2's first Y write (attn==64 gate at lstm2 init). Deadlock-free:
//  32 spinning lstm blocks << 512 resident block slots; gemm never waits.

typedef unsigned short u16;
typedef unsigned int u32;
typedef __bf16 v8bf __attribute__((ext_vector_type(8)));
typedef float  v4f  __attribute__((ext_vector_type(4)));
typedef unsigned short u16x8 __attribute__((ext_vector_type(8)));
typedef unsigned short u16x4 __attribute__((ext_vector_type(4)));
typedef unsigned int   u32x2 __attribute__((ext_vector_type(2)));

#define GLP(p) ((const __attribute__((address_space(1))) void*)(p))
#define LDSP(p) ((__attribute__((address_space(3))) void*)(p))

__device__ __forceinline__ float b2f(u16 b){
  return __builtin_bit_cast(float, ((unsigned)b) << 16);
}
__device__ __forceinline__ u16 f2b(float x){           // RNE f32->bf16
  unsigned u = __builtin_bit_cast(unsigned, x);
  unsigned r = (u + 0x7FFFu + ((u >> 16) & 1u)) >> 16;
  return (u16)r;
}
__device__ __forceinline__ u16 f2b_fast(float x){      // RNE via HW cvt_pk
  u32 t;
  asm("v_cvt_pk_bf16_f32 %0, %1, 0" : "=v"(t) : "v"(x));
  return (u16)t;
}
// LDS-only workgroup barrier
__device__ __forceinline__ void lds_only_barrier(){
  __builtin_amdgcn_fence(__ATOMIC_RELEASE, "workgroup", "local");
  __builtin_amdgcn_s_barrier();
  __builtin_amdgcn_fence(__ATOMIC_ACQUIRE, "workgroup", "local");
}

// ---------------- prep: conv_weights (blocks 0..1023) ∪ embed_gather ----------------
__global__ __launch_bounds__(256) void prep_kernel(
    const float* __restrict__ Wih1f, const float* __restrict__ Wih1b,
    const float* __restrict__ bih1f, const float* __restrict__ bhh1f,
    const float* __restrict__ bih1b, const float* __restrict__ bhh1b,
    const float* __restrict__ Wih2f, const float* __restrict__ Wih2b,
    const float* __restrict__ bih2f, const float* __restrict__ bhh2f,
    const float* __restrict__ bih2b, const float* __restrict__ bhh2b,
    u16* __restrict__ W1cat, u16* __restrict__ WAcat,
    float* __restrict__ b1cat, float* __restrict__ b2cat,
    const int* __restrict__ sent, const float* __restrict__ emb,
    u16* __restrict__ X)
{
  if (blockIdx.x < 1024){
    int gid = blockIdx.x * 256 + threadIdx.x;   // 1024*256 = 262144
    int j = gid >> 8, e = gid & 255;            // j = permuted column jp
    int dirj = j >> 9, u = (j >> 2) & 127, g = j & 3;
    int r = g*128 + u;                          // 0..511
    float w1 = dirj ? Wih1b[r*256 + e] : Wih1f[r*256 + e];
    float wa = dirj ? Wih2b[(long)r*512 + e] : Wih2f[(long)r*512 + e];
    W1cat[gid] = f2b(w1);
    WAcat[gid] = f2b(wa);
    if (e == 0){
      b1cat[j] = dirj ? (bih1b[r] + bhh1b[r]) : (bih1f[r] + bhh1f[r]);
      b2cat[j] = dirj ? (bih2b[r] + bhh2b[r]) : (bih2f[r] + bhh2f[r]);
    }
  } else {
    int w = threadIdx.x >> 6, lane = threadIdx.x & 63;
    long i = (long)(blockIdx.x - 1024) * 4 + w; // row of X, 0..65535
    int idx = sent[i];
    const float4* src = (const float4*)(emb + (long)idx * 256);
    float4 v = src[lane];
    u16x4 o; o[0] = f2b(v.x); o[1] = f2b(v.y); o[2] = f2b(v.z); o[3] = f2b(v.w);
    *(u16x4*)(X + i*256 + lane*4) = o;
  }
}

// ---- bf16 MFMA GEMM body (R20-verified, tid parameterized for half-blocks) ----
__device__ __forceinline__ void gemm_body(
    u16* smem, const u16* __restrict__ A, const u16* __restrict__ Bm,
    const float* __restrict__ bias, u16* __restrict__ Gp,
    long mblk, int nt, int tid)
{
  u16* As = smem;
  u16* Bs = smem + 8192;
  int w = tid >> 6, lane = tid & 63;
  int lq = lane & 15, quad = lane >> 4;
  int wm = w & 1, wn = w >> 1;
  long m0 = mblk * 128;
  int n0 = nt * 128;
  const int K = 256;
  v4f acc[4][4];
  v4f zero = {0.f, 0.f, 0.f, 0.f};
#pragma unroll
  for (int i=0;i<4;i++)
#pragma unroll
    for (int j=0;j<4;j++) acc[i][j] = zero;

  int rloc = lane >> 3;                        // 0..7 row within wave block
  int p    = lane & 7;                         // LDS chunk position

  for (int k0 = 0; k0 < K; k0 += 64){
#pragma unroll
    for (int c = 0; c < 4; c++){
      int r0  = c*32 + w*8;                    // wave's first row this iter
      int row = r0 + rloc;
      int ch  = p ^ (row & 7);                 // pre-swizzled source chunk
      const u16* ga = A  + (m0+row)*K + k0 + ch*8;
      const u16* gb = Bm + ((long)(n0+row))*K + k0 + ch*8;
      __builtin_amdgcn_global_load_lds(GLP(ga), LDSP(As + r0*64), 16, 0, 0);
      __builtin_amdgcn_global_load_lds(GLP(gb), LDSP(Bs + r0*64), 16, 0, 0);
    }
    __syncthreads();
#pragma unroll
    for (int s = 0; s < 2; s++){
      v8bf af[4], bf_[4];
#pragma unroll
      for (int i=0;i<4;i++){
        int row = wm*64 + i*16 + lq;
        int ch  = (s*4 + quad) ^ (row & 7);
        af[i] = __builtin_bit_cast(v8bf, *(const u16x8*)(As + row*64 + ch*8));
      }
#pragma unroll
      for (int j=0;j<4;j++){
        int row = wn*64 + j*16 + lq;
        int ch  = (s*4 + quad) ^ (row & 7);
        bf_[j] = __builtin_bit_cast(v8bf, *(const u16x8*)(Bs + row*64 + ch*8));
      }
#pragma unroll
      for (int i=0;i<4;i++)
#pragma unroll
        for (int j=0;j<4;j++)
          acc[i][j] = __builtin_amdgcn_mfma_f32_16x16x32_bf16(af[i], bf_[j], acc[i][j], 0, 0, 0);
    }
    __syncthreads();
  }

  // ---- epilogue: scatter into LDS window, then dense copy-out (R16/R20) ----
  int dirj = n0 >> 9;
  int u0v  = (n0 & 511) >> 2;   // 32-aligned
  int v0   = u0v >> 4;          // v_start, in {0,2,4,6}
#pragma unroll
  for (int jt=0;jt<4;jt++){
    int j = n0 + wn*64 + jt*16 + lq;          // permuted column
    float bv = bias[j];
    int u = (j >> 2) & 127, g = j & 3;
    int tW = ((u>>4) - v0)*64 + ((u>>2)&3)*16 + (u&3)*4;   // 0..124
#pragma unroll
    for (int i16=0;i16<4;i16++){
#pragma unroll
      for (int r2=0;r2<4;r2++){
        int il = wm*64 + i16*16 + quad*4 + r2;   // local row 0..127
        int bb = il & 63;
        int l_local = il >> 6;                   // == wm
        int off16 = l_local*8192 + (bb>>2)*512 + (tW + (bb&3))*4 + g;
        smem[off16] = f2b(acc[i16][jt][r2] + bv);
      }
    }
  }
  __syncthreads();
  long lbase = m0 >> 6;
#pragma unroll
  for (int seg=0; seg<8; seg++){
    int off16 = (seg*256 + tid) * 8;             // 16B granule, contiguous LDS read
    int l_local = off16 >> 13;
    int grp_local = (off16 >> 9) & 15;
    int rest = off16 & 511;
    long gdst = ((long)(dirj*16 + grp_local) << 21) + ((lbase + l_local) << 11)
              + (long)v0*256 + rest;
    *(u16x8*)(Gp + gdst) = *(const u16x8*)(smem + off16);
  }
}

// ---- attention body (R20-verified math; 512-thr safe: dup threads mirror
// pure same-value stores; reductions guarded by REAL threadIdx < s) ----
__device__ __forceinline__ void attn_body(
    u16* smem, const u16* __restrict__ y1, const float* __restrict__ catc,
    const float* __restrict__ Wih2f, const float* __restrict__ Wih2b,
    float* __restrict__ sT, float* __restrict__ proj, int b)
{
  float* catv = (float*)smem;            // 256 f
  float* ev   = catv + 256;              // 1024 f
  float* red  = ev + 1024;               // 256 f
  int tt = threadIdx.x;                  // 0..511
  int t  = tt & 255;
  catv[t] = catc[b*256 + t];             // dup same-value store: benign
  __syncthreads();
  float evl[4];
#pragma unroll
  for (int r2=0;r2<4;r2++){
    int l = t + r2*256;
    const u16x8* row = (const u16x8*)(y1 + ((long)l*64 + b)*256);
    float acc = 0.f;
    for (int f8=0; f8<32; f8++){
      u16x8 v = row[f8];
#pragma unroll
      for (int k=0;k<8;k++) acc += b2f(v[k]) * catv[f8*8+k];
    }
    ev[l] = acc; evl[r2] = acc;          // dup same-value store: benign
  }
  float mx = fmaxf(fmaxf(evl[0],evl[1]), fmaxf(evl[2],evl[3]));
  red[t] = mx;                            // dup same-value store: benign
  __syncthreads();
  for (int s=128; s>0; s>>=1){ if (tt < s) red[tt] = fmaxf(red[tt], red[tt+s]); __syncthreads(); }
  float m = red[0];
  __syncthreads();
  float sum = 0.f;
#pragma unroll
  for (int r2=0;r2<4;r2++){
    int l = t + r2*256;
    float e = __expf(ev[l] - m);
    ev[l] = e; sum += e;                  // dup same-value store: benign
  }
  red[t] = sum;
  __syncthreads();
  for (int s=128; s>0; s>>=1){ if (tt < s) red[tt] += red[tt+s]; __syncthreads(); }
  float rz = __builtin_amdgcn_rcpf(red[0]);
#pragma unroll
  for (int r2=0;r2<4;r2++){
    int l = t + r2*256;
    sT[(long)l*64 + b] = ev[l] * rz;      // dup same-value store: benign
  }
#pragma unroll
  for (int r2=0;r2<4;r2++){
    int j = t + r2*256;
    const float* wr = (j < 512) ? (Wih2f + (long)j*512 + 256)
                                : (Wih2b + (long)(j-512)*512 + 256);
    const float4* w4 = (const float4*)wr;
    float acc = 0.f;
#pragma unroll 8
    for (int f4=0; f4<64; f4++){
      float4 v = w4[f4];
      acc += v.x*catv[f4*4+0] + v.y*catv[f4*4+1] + v.z*catv[f4*4+2] + v.w*catv[f4*4+3];
    }
    proj[b*1024 + j] = acc;               // dup same-value store: benign
  }
}

// ---------------- persistent BiLSTM body (R20-verified + G/attn gating) ----------------
// sc layout (ints): [0..512) per-mblk tile count (target 8), [512] total
// (target 4096), [513] attn blocks done (target 64).
__device__ __forceinline__ void lstm_body(
    u16* smem, const u16* __restrict__ G,
    const float* __restrict__ WhhF, const float* __restrict__ WhhB,
    const float* __restrict__ h0, const float* __restrict__ c0,
    const float* __restrict__ sT, const float* __restrict__ proj,
    u16* __restrict__ Y, float* __restrict__ catOut,
    int* __restrict__ sc, int blk)
{
  int dir = blk >> 4, bg = blk & 15, b0 = bg * 4;
  int tid = threadIdx.x, v = tid >> 6, lane = tid & 63;
  int quad = lane >> 4, lq = lane & 15;
  int b3 = lq & 3, tp = lq >> 2;
  int U = v*16 + 4*quad + tp;                 // this thread's hidden unit
  int batch = b0 + b3;
  const float* Whh = dir ? WhhB : WhhF;

  u16* hbuf = smem;                           // [2][576] in u16, stride 144/row

  // A-frags (overlaps with gemm producer runtime - good)
  v8bf Af[4][4];
  {
    int gate_ = lq & 3;
    int ur = v*16 + 4*(lq>>2);
#pragma unroll
    for (int tau=0;tau<4;tau++){
      const float* wr = Whh + (long)(gate_*128 + ur + tau)*128;
#pragma unroll
      for (int ks=0;ks<4;ks++){
        union { u32 w[4]; u16x8 h; } uu;
#pragma unroll
        for (int jj=0;jj<4;jj++){
          float x0 = wr[ks*32 + quad*8 + 2*jj];
          float x1 = wr[ks*32 + quad*8 + 2*jj + 1];
          asm("v_cvt_pk_bf16_f32 %0, %1, %2" : "=v"(uu.w[jj]) : "v"(x0), "v"(x1));
        }
        Af[tau][ks] = __builtin_bit_cast(v8bf, uu.h);
      }
    }
  }

  int wOff = b3*144 + U;                      // own cell
  int rOff[4];
#pragma unroll
  for (int ks=0;ks<4;ks++) rOff[ks] = b3*144 + (ks*4 + quad)*8;

  float cc = c0[dir*8192 + batch*128 + U];
  u16 h0b = f2b(h0[dir*8192 + batch*128 + U]);
  hbuf[wOff] = h0b;                           // slot 0

  bool att = (proj != nullptr);
  // attn gate: sT/proj fully written before any read (and before first Y write)
  if (att){
    while (__hip_atomic_load(&sc[513], __ATOMIC_RELAXED, __HIP_MEMORY_SCOPE_AGENT) < 64)
      __builtin_amdgcn_s_sleep(2);
    __builtin_amdgcn_fence(__ATOMIC_ACQUIRE, "agent");
  }
  float pr[4];
  if (att){
#pragma unroll
    for (int g=0;g<4;g++)
      pr[g] = 64.0f * proj[(long)batch*1024 + dir*512 + g*128 + U];
  }

  long dl = dir ? -1 : 1;
  long l0 = dir ? 1023 : 0;

  // G gating state
  bool all_done = false;
  int lastm = (int)(l0 >> 1);
  // initial gate: l0 and l0+dl share mblk
  {
    if (__hip_atomic_load(&sc[512], __ATOMIC_RELAXED, __HIP_MEMORY_SCOPE_AGENT) >= 4096){
      all_done = true;
    } else {
      while (__hip_atomic_load(&sc[lastm], __ATOMIC_RELAXED, __HIP_MEMORY_SCOPE_AGENT) < 8)
        __builtin_amdgcn_s_sleep(2);
    }
    __builtin_amdgcn_fence(__ATOMIC_ACQUIRE, "agent");
  }

  // running pointers (+const step): G prefetch, Y store, sT scalar
  const u16* GbU = G + ((size_t)blk << 21);   // uniform
  int gvo = tid * 4;                          // fixed per-thread, u16 units
  u16x4 gbuf[2];
  gbuf[0] = *(const u16x4*)(GbU + ((size_t)l0 << 11) + gvo);
  gbuf[1] = *(const u16x4*)(GbU + ((size_t)(l0 + dl) << 11) + gvo);
  const u16* gp = GbU + ((size_t)(l0 + 2*dl) << 11) + gvo;  // runs 2 past end: ws-internal
  long gstep = dl << 11;
  long lpf = l0 + 2*dl;                       // prefetch l index (for gating only)

  u16* yp = Y + l0*16384 + batch*256 + dir*128 + U;
  long ystep = dl * 16384;

  float sv[2] = {0.f, 0.f};
  const float* sp = nullptr;
  long sstep = dl * 64;
  if (att){
    sv[0] = sT[l0*64 + batch];
    sv[1] = sT[(l0 + dl)*64 + batch];
    sp = sT + (l0 + 2*dl)*64 + batch;
  }

  const float NL2E = -1.4426950408889634f;
  const float N2L2E = -2.8853900817779268f;
  v4f zero4 = {0.f, 0.f, 0.f, 0.f};
  __syncthreads();   // full barrier once before the loop (h0 writes + init)

#pragma unroll 2
  for (int it = 0; it < 1024; ++it){
    int slot = it & 1;
    // h fragments FIRST: start LDS latency before the scalar work.
    v8bf bh[4];
#pragma unroll
    for (int ks=0;ks<4;ks++)
      bh[ks] = __builtin_bit_cast(v8bf, *(const u16x8*)(&hbuf[slot*576 + rOff[ks]]));
    // gates for this step (bit-trick unpack)
    float gc[4];
    {
      u32x2 gw = __builtin_bit_cast(u32x2, gbuf[slot]);
      gc[0] = __builtin_bit_cast(float, gw[0] << 16);
      gc[1] = __builtin_bit_cast(float, gw[0] & 0xFFFF0000u);
      gc[2] = __builtin_bit_cast(float, gw[1] << 16);
      gc[3] = __builtin_bit_cast(float, gw[1] & 0xFFFF0000u);
    }
    // G gate for the prefetch target (poll only at mblk boundaries)
    if ((unsigned long)lpf < 1024ul){
      int m = (int)((unsigned long)lpf >> 1);
      if (m != lastm){
        if (!all_done){
          if (__hip_atomic_load(&sc[512], __ATOMIC_RELAXED, __HIP_MEMORY_SCOPE_AGENT) >= 4096){
            all_done = true;
          } else {
            while (__hip_atomic_load(&sc[m], __ATOMIC_RELAXED, __HIP_MEMORY_SCOPE_AGENT) < 8)
              __builtin_amdgcn_s_sleep(2);
          }
          __builtin_amdgcn_fence(__ATOMIC_ACQUIRE, "agent");
        }
        lastm = m;
      }
    }
    gbuf[slot] = *(const u16x4*)gp; gp += gstep; lpf += dl;   // prefetch it+2
    float s = 0.f;
    if (att){
      s = sv[slot];
      sv[slot] = *sp; sp += sstep;
    }
    // 4 independent MFMA chains (tau = 0..3)
    v4f a0 = zero4, a1 = zero4, a2 = zero4, a3 = zero4;
    __builtin_amdgcn_s_setprio(1);
#pragma unroll
    for (int ks=0;ks<4;ks++){
      a0 = __builtin_amdgcn_mfma_f32_16x16x32_bf16(Af[0][ks], bh[ks], a0, 0,0,0);
      a1 = __builtin_amdgcn_mfma_f32_16x16x32_bf16(Af[1][ks], bh[ks], a1, 0,0,0);
      a2 = __builtin_amdgcn_mfma_f32_16x16x32_bf16(Af[2][ks], bh[ks], a2, 0,0,0);
      a3 = __builtin_amdgcn_mfma_f32_16x16x32_bf16(Af[3][ks], bh[ks], a3, 0,0,0);
    }
    __builtin_amdgcn_s_setprio(0);

    // select acc[tp] at own column (bit-exact: D cols are broadcast copies)
    float val[4];
#pragma unroll
    for (int r=0;r<4;r++){
      float x01 = (tp & 1) ? a1[r] : a0[r];
      float x23 = (tp & 1) ? a3[r] : a2[r];
      float x   = (tp & 2) ? x23 : x01;
      val[r] = x + gc[r];
    }
    if (att){
#pragma unroll
      for (int r=0;r<4;r++) val[r] = fmaf(s, pr[r], val[r]);
    }

    float i_ = val[0], f_ = val[1], g_ = val[2], o_ = val[3];
    float ef = __builtin_amdgcn_exp2f(f_ * NL2E);
    float ei = __builtin_amdgcn_exp2f(i_ * NL2E);
    float eg = __builtin_amdgcn_exp2f(fminf(g_ * N2L2E, 115.0f));
    float sf = __builtin_amdgcn_rcpf(1.0f + ef);
    float pp = (1.0f - eg) * __builtin_amdgcn_rcpf((1.0f + ei) * (1.0f + eg));
    float c2 = fmaf(cc, sf, pp);
    cc = c2;
    float eo = __builtin_amdgcn_exp2f(o_ * NL2E);
    float ec = __builtin_amdgcn_exp2f(fminf(c2 * N2L2E, 115.0f));
    float hv = (1.0f - ec) * __builtin_amdgcn_rcpf((1.0f + eo) * (1.0f + ec));

    u16 hb = f2b_fast(hv);
    hbuf[(slot^1)*576 + wOff] = hb;
    *yp = hb; yp += ystep;                    // gated: mblk(l) confirmed 2 steps ago
    lds_only_barrier();
  }
  if (catOut)
    catOut[(long)batch*256 + dir*128 + U] = cc;
}

// ---- fused1: lstm1 [0,32) ∪ gemm1 [32,2080) (2 tiles per block) ----
// Tile order: o alternates l-ends (o even -> mblk o/2, odd -> 511-o/2).
__global__ __launch_bounds__(512, 4) void fused1(
    const u16* __restrict__ X, const u16* __restrict__ W1cat,
    const float* __restrict__ b1cat, u16* __restrict__ Gp,
    const float* __restrict__ WhhF, const float* __restrict__ WhhB,
    const float* __restrict__ h0, const float* __restrict__ c0,
    u16* __restrict__ Y, float* __restrict__ catOut, int* __restrict__ sc)
{
  __shared__ __align__(16) u16 smem[32768];
  int bx = blockIdx.x;
  if (bx < 32){
    lstm_body(smem, Gp, WhhF, WhhB, h0, c0, nullptr, nullptr, Y, catOut, sc, bx);
  } else {
    int bi = bx - 32;
    int half = threadIdx.x >> 8;
    int tid  = threadIdx.x & 255;
    int tau = bi*2 + half;                    // 0..4095
    int o = tau >> 3, nt = tau & 7;
    int mblk = (o & 1) ? 511 - (o >> 1) : (o >> 1);
    gemm_body(smem + half*16384, X, W1cat, b1cat, Gp, (long)mblk, nt, tid);
    __syncthreads();
    if (tid == 0){                            // threads 0 and 256 publish
      __threadfence();
      atomicAdd(&sc[mblk], 1);
      atomicAdd(&sc[512], 1);
    }
  }
}

// ---- fused2: attn [0,64) ∪ lstm2 [64,96) ∪ gemm2 [96,2144) ----
__global__ __launch_bounds__(512, 4) void fused2(
    const u16* __restrict__ y1, const float* __restrict__ catc,
    const float* __restrict__ Wih2f, const float* __restrict__ Wih2b,
    float* __restrict__ sT, float* __restrict__ proj,
    const u16* __restrict__ WAcat, const float* __restrict__ b2cat,
    u16* __restrict__ Gp,
    const float* __restrict__ WhhF, const float* __restrict__ WhhB,
    const float* __restrict__ h02, const float* __restrict__ c02,
    u16* __restrict__ Y, int* __restrict__ sc)
{
  __shared__ __align__(16) u16 smem[32768];
  int bx = blockIdx.x;
  if (bx < 64){
    attn_body(smem, y1, catc, Wih2f, Wih2b, sT, proj, bx);
    __syncthreads();
    if (threadIdx.x == 0){
      __threadfence();
      atomicAdd(&sc[513], 1);
    }
  } else if (bx < 96){
    lstm_body(smem, Gp, WhhF, WhhB, h02, c02, sT, proj, Y, nullptr, sc, bx - 64);
  } else {
    int bi = bx - 96;
    int half = threadIdx.x >> 8;
    int tid  = threadIdx.x & 255;
    int tau = bi*2 + half;
    int o = tau >> 3, nt = tau & 7;
    int mblk = (o & 1) ? 511 - (o >> 1) : (o >> 1);
    gemm_body(smem + half*16384, y1, WAcat, b2cat, Gp, (long)mblk, nt, tid);
    __syncthreads();
    if (tid == 0){
      __threadfence();
      atomicAdd(&sc[mblk], 1);
      atomicAdd(&sc[512], 1);
    }
  }
}

// ---------------- feats = exp(out2 @ Wout.T + bout) (CRF consumes exp domain) ----------------
__global__ __launch_bounds__(256) void featk(const u16* __restrict__ y2,
    const float* __restrict__ Wout, const float* __restrict__ bout, float* __restrict__ feats)
{
  __shared__ float wlds[1280];
  int t = threadIdx.x;
  for (int k=t;k<1280;k+=256) wlds[k] = Wout[k];
  __syncthreads();
  long i = (long)blockIdx.x*256 + t;
  const u16x8* row = (const u16x8*)(y2 + i*256);
  float acc[5] = {0.f,0.f,0.f,0.f,0.f};
  for (int f8=0; f8<32; f8++){
    u16x8 v = row[f8];
#pragma unroll
    for (int k=0;k<8;k++){
      float x = b2f(v[k]);
      int f = f8*8 + k;
#pragma unroll
      for (int c=0;c<5;c++) acc[c] += x * wlds[c*256 + f];
    }
  }
#pragma unroll
  for (int c=0;c<5;c++) feats[i*5 + c] = __expf(acc[c] + bout[c]);
}

// ---------------- CRF forward, exp domain: sc[c] = M + ln E[c] ----------------
__global__ void crf_kernel(const float* __restrict__ feats, const float* __restrict__ masks,
                           const float* __restrict__ trans, float* __restrict__ out)
{
  int b = threadIdx.x;  // 64
  float etr[5][5], tr4[5];
#pragma unroll
  for (int c=0;c<5;c++)
#pragma unroll
    for (int cp=0;cp<5;cp++) etr[c][cp] = __expf(trans[c*5+cp]);  // e^-10000 -> 0
#pragma unroll
  for (int cp=0;cp<5;cp++) tr4[cp] = trans[4*5+cp];   // STOP row
  float E[5] = {0.f, 0.f, 0.f, 1.f, 0.f};             // exp(sc), START=3
  float M = 0.f;
  const float* fpB = feats + (long)b*5120;
  float ftn[5], mtn;
#pragma unroll
  for (int c=0;c<5;c++) ftn[c] = fpB[c];
  mtn = masks[b*1024];
  for (int l=0;l<1024;l++){
    float ft[5]; float mt = mtn;
#pragma unroll
    for (int c=0;c<5;c++) ft[c] = ftn[c];
    if (l < 1023){
      const float* fp = fpB + (l + 1)*5;
#pragma unroll
      for (int c=0;c<5;c++) ftn[c] = fp[c];
      mtn = masks[b*1024 + l + 1];
    }
    float En[5];
#pragma unroll
    for (int c=0;c<5;c++){
      float S = E[0]*etr[c][0];
#pragma unroll
      for (int cp=1;cp<5;cp++) S = fmaf(E[cp], etr[c][cp], S);
      En[c] = S * ft[c];
    }
    bool take = (mt > 0.5f);
#pragma unroll
    for (int c=0;c<5;c++) E[c] = take ? En[c] : E[c];
    if ((l & 7) == 7){
      // exact power-of-2 renorm
      float mx = fmaxf(fmaxf(fmaxf(E[0],E[1]), fmaxf(E[2],E[3])), E[4]);
      int k = (int)((__builtin_bit_cast(unsigned, mx) >> 23) & 0xFFu) - 127;
      float s = __builtin_bit_cast(float, (unsigned)(127 - k) << 23);
#pragma unroll
      for (int c=0;c<5;c++) E[c] *= s;
      M = fmaf((float)k, 0.6931471805599453f, M);
    }
  }
  float Sf = 0.f;
#pragma unroll
  for (int cp=0;cp<5;cp++) Sf = fmaf(E[cp], __expf(tr4[cp]), Sf);
  out[b] = M + __logf(Sf);
}

// ---------------- launcher ----------------
extern "C" void kernel_launch(void* const* d_in, const int* in_sizes, int n_in,
                              void* d_out, int out_size, void* d_ws, size_t ws_size,
                              hipStream_t stream)
{
  const int*   sent  = (const int*)  d_in[0];
  const float* masks = (const float*)d_in[1];
  const float* emb   = (const float*)d_in[2];
  const float* Wih1f = (const float*)d_in[3];
  const float* Whh1f = (const float*)d_in[4];
  const float* bih1f = (const float*)d_in[5];
  const float* bhh1f = (const float*)d_in[6];
  const float* Wih1b = (const float*)d_in[7];
  const float* Whh1b = (const float*)d_in[8];
  const float* bih1b = (const float*)d_in[9];
  const float* bhh1b = (const float*)d_in[10];
  const float* Wih2f = (const float*)d_in[11];
  const float* Whh2f = (const float*)d_in[12];
  const float* bih2f = (const float*)d_in[13];
  const float* bhh2f = (const float*)d_in[14];
  const float* Wih2b = (const float*)d_in[15];
  const float* Whh2b = (const float*)d_in[16];
  const float* bih2b = (const float*)d_in[17];
  const float* bhh2b = (const float*)d_in[18];
  const float* Wout  = (const float*)d_in[19];
  const float* bout  = (const float*)d_in[20];
  const float* trans = (const float*)d_in[21];
  const float* h0    = (const float*)d_in[22];
  const float* c0    = (const float*)d_in[23];
  const float* h02   = (const float*)d_in[24];
  const float* c02   = (const float*)d_in[25];
  float* out = (float*)d_out;

  // workspace layout (aliased: X/y1/y2 share, G per layer shares). ~170.7 MB.
  char* ws = (char*)d_ws;
  u16*   Ybuf  = (u16*)(ws + 0);              // 33,554,432 B: X, then y1, then y2
  u16*   Gbuf  = (u16*)(ws + 33554432);       // 134,217,728 B: G'' per layer
  u16*   W1cat = (u16*)(ws + 167772160);      // 524,288 B
  u16*   WAcat = (u16*)(ws + 168296448);      // 524,288 B
  float* b1cat = (float*)(ws + 168820736);    // 4,096 B
  float* b2cat = (float*)(ws + 168824832);    // 4,096 B
  float* catcb = (float*)(ws + 168828928);    // 65,536 B
  float* sbuf  = (float*)(ws + 168894464);    // 262,144 B  (sT[l][64])
  float* projb = (float*)(ws + 169156608);    // 262,144 B
  float* featb = (float*)(ws + 169418752);    // 1,310,720 B (counters live in
                                              //  first 8KB until featk overwrites)
  int* sc1 = (int*)featb;                     // [0..512) cnt, [512] tot, [513] attn
  int* sc2 = sc1 + 1024;

  hipMemsetAsync(featb, 0, 8192, stream);     // zero both counter sets each replay
  prep_kernel<<<17408, 256, 0, stream>>>(Wih1f, Wih1b, bih1f, bhh1f, bih1b, bhh1b,
                                         Wih2f, Wih2b, bih2f, bhh2f, bih2b, bhh2b,
                                         W1cat, WAcat, b1cat, b2cat, sent, emb, Ybuf);
  fused1<<<2080, 512, 0, stream>>>(Ybuf, W1cat, b1cat, Gbuf,
                                   Whh1f, Whh1b, h0, c0, Ybuf, catcb, sc1);
  fused2<<<2144, 512, 0, stream>>>(Ybuf, catcb, Wih2f, Wih2b, sbuf, projb,
                                   WAcat, b2cat, Gbuf,
                                   Whh2f, Whh2b, h02, c02, Ybuf, sc2);
  featk<<<256, 256, 0, stream>>>(Ybuf, Wout, bout, featb);
  crf_kernel<<<1, 64, 0, stream>>>(featb, masks, trans, out);
}

// Round 12
// 1457.294 us; speedup vs baseline: 1.5196x; 1.5196x over previous
//
#include <hip/hip_runtime.h>
#include <hip/hip_bf16.h>

// BiLSTM-CRF forward. B=64, L=1024, E=256, H=128 (per dir), C=5, V=32000.
// R24 = R20 resubmitted verbatim (R23 was an infra failure; R20 verified at
// 1462.6us, absmax 0.0 in Round 8).
// Session ledger:
//  - lstm_layer floor: 32 exclusive CUs, ~1195 cyc/step vs ~620 cyc per-CU
//    MFMA weight-sweep floor (invariant to packing; R13/R22 proved sharing
//    CUs with other work inflates the latency-critical step).
//  - Falsified: R13 2-rec/CU pairing, R17 persistent-A-slab + embed fusion,
//    R18 global_load_lds staging, R21/R22 producer-consumer fusion (correct
//    but 1.5x slower - CU contention).
//  - Kept wins: R15 micro set (select-tree redistribute, padded hbuf
//    stride-144 (conflicts 0), cvt_pk conversions, exp-domain featk+CRF),
//    R16 de-scatter epilogue, R19 launch fusions {conv ∪ embed},
//    {attn ∪ gemm2} + running-pointer lstm addressing.

typedef unsigned short u16;
typedef unsigned int u32;
typedef __bf16 v8bf __attribute__((ext_vector_type(8)));
typedef float  v4f  __attribute__((ext_vector_type(4)));
typedef unsigned short u16x8 __attribute__((ext_vector_type(8)));
typedef unsigned short u16x4 __attribute__((ext_vector_type(4)));
typedef unsigned int   u32x2 __attribute__((ext_vector_type(2)));

#define GLP(p) ((const __attribute__((address_space(1))) void*)(p))
#define LDSP(p) ((__attribute__((address_space(3))) void*)(p))

__device__ __forceinline__ float b2f(u16 b){
  return __builtin_bit_cast(float, ((unsigned)b) << 16);
}
__device__ __forceinline__ u16 f2b(float x){           // RNE f32->bf16
  unsigned u = __builtin_bit_cast(unsigned, x);
  unsigned r = (u + 0x7FFFu + ((u >> 16) & 1u)) >> 16;
  return (u16)r;
}
__device__ __forceinline__ u16 f2b_fast(float x){      // RNE via HW cvt_pk
  u32 t;
  asm("v_cvt_pk_bf16_f32 %0, %1, 0" : "=v"(t) : "v"(x));
  return (u16)t;
}
// LDS-only workgroup barrier
__device__ __forceinline__ void lds_only_barrier(){
  __builtin_amdgcn_fence(__ATOMIC_RELEASE, "workgroup", "local");
  __builtin_amdgcn_s_barrier();
  __builtin_amdgcn_fence(__ATOMIC_ACQUIRE, "workgroup", "local");
}

// ---------------- prep: conv_weights (blocks 0..1023) ∪ embed_gather ----------------
// conv: permuted col jp: dirj=jp>>9, u=(jp>>2)&127, g=jp&3; original row r=g*128+u
__global__ __launch_bounds__(256) void prep_kernel(
    const float* __restrict__ Wih1f, const float* __restrict__ Wih1b,
    const float* __restrict__ bih1f, const float* __restrict__ bhh1f,
    const float* __restrict__ bih1b, const float* __restrict__ bhh1b,
    const float* __restrict__ Wih2f, const float* __restrict__ Wih2b,
    const float* __restrict__ bih2f, const float* __restrict__ bhh2f,
    const float* __restrict__ bih2b, const float* __restrict__ bhh2b,
    u16* __restrict__ W1cat, u16* __restrict__ WAcat,
    float* __restrict__ b1cat, float* __restrict__ b2cat,
    const int* __restrict__ sent, const float* __restrict__ emb,
    u16* __restrict__ X)
{
  if (blockIdx.x < 1024){
    int gid = blockIdx.x * 256 + threadIdx.x;   // 1024*256 = 262144
    int j = gid >> 8, e = gid & 255;            // j = permuted column jp
    int dirj = j >> 9, u = (j >> 2) & 127, g = j & 3;
    int r = g*128 + u;                          // 0..511
    float w1 = dirj ? Wih1b[r*256 + e] : Wih1f[r*256 + e];
    float wa = dirj ? Wih2b[(long)r*512 + e] : Wih2f[(long)r*512 + e];
    W1cat[gid] = f2b(w1);
    WAcat[gid] = f2b(wa);
    if (e == 0){
      b1cat[j] = dirj ? (bih1b[r] + bhh1b[r]) : (bih1f[r] + bhh1f[r]);
      b2cat[j] = dirj ? (bih2b[r] + bhh2b[r]) : (bih2f[r] + bhh2f[r]);
    }
  } else {
    int w = threadIdx.x >> 6, lane = threadIdx.x & 63;
    long i = (long)(blockIdx.x - 1024) * 4 + w; // row of X, 0..65535
    int idx = sent[i];
    const float4* src = (const float4*)(emb + (long)idx * 256);
    float4 v = src[lane];
    u16x4 o; o[0] = f2b(v.x); o[1] = f2b(v.y); o[2] = f2b(v.z); o[3] = f2b(v.w);
    *(u16x4*)(X + i*256 + lane*4) = o;
  }
}

// ---- bf16 MFMA GEMM body, A[MxK] rm, Bperm[NxK] rm, +bias -> G''[grp][l][thr][4] ----
// permuted col j: dirj=j>>9, u=(j>>2)&127, g=j&3
// u -> v=u>>4, quad=(u>>2)&3, tp=u&3; thr = v*64+quad*16+tp*4+(b&3)
// grp = dirj*16 + (b>>2); off = (grp<<21) + (l<<11) + thr*4 + g  (u16 units)
// Staging: global_load_lds w=16, pre-swizzled source chunk (ch = p ^ (row&7)).
// Epilogue: LDS de-scatter -> dense 16B stores (R16-verified arithmetic).
__device__ __forceinline__ void gemm_body(
    u16* smem, const u16* __restrict__ A, const u16* __restrict__ Bm,
    const float* __restrict__ bias, u16* __restrict__ Gp,
    long mblk, int nt)
{
  u16* As = smem;
  u16* Bs = smem + 8192;
  int tid = threadIdx.x;
  int w = tid >> 6, lane = tid & 63;
  int lq = lane & 15, quad = lane >> 4;
  int wm = w & 1, wn = w >> 1;
  long m0 = mblk * 128;
  int n0 = nt * 128;
  const int K = 256;
  v4f acc[4][4];
  v4f zero = {0.f, 0.f, 0.f, 0.f};
#pragma unroll
  for (int i=0;i<4;i++)
#pragma unroll
    for (int j=0;j<4;j++) acc[i][j] = zero;

  int rloc = lane >> 3;                        // 0..7 row within wave block
  int p    = lane & 7;                         // LDS chunk position

  for (int k0 = 0; k0 < K; k0 += 64){
#pragma unroll
    for (int c = 0; c < 4; c++){
      int r0  = c*32 + w*8;                    // wave's first row this iter
      int row = r0 + rloc;
      int ch  = p ^ (row & 7);                 // pre-swizzled source chunk
      const u16* ga = A  + (m0+row)*K + k0 + ch*8;
      const u16* gb = Bm + ((long)(n0+row))*K + k0 + ch*8;
      __builtin_amdgcn_global_load_lds(GLP(ga), LDSP(As + r0*64), 16, 0, 0);
      __builtin_amdgcn_global_load_lds(GLP(gb), LDSP(Bs + r0*64), 16, 0, 0);
    }
    __syncthreads();
#pragma unroll
    for (int s = 0; s < 2; s++){
      v8bf af[4], bf_[4];
#pragma unroll
      for (int i=0;i<4;i++){
        int row = wm*64 + i*16 + lq;
        int ch  = (s*4 + quad) ^ (row & 7);
        af[i] = __builtin_bit_cast(v8bf, *(const u16x8*)(As + row*64 + ch*8));
      }
#pragma unroll
      for (int j=0;j<4;j++){
        int row = wn*64 + j*16 + lq;
        int ch  = (s*4 + quad) ^ (row & 7);
        bf_[j] = __builtin_bit_cast(v8bf, *(const u16x8*)(Bs + row*64 + ch*8));
      }
#pragma unroll
      for (int i=0;i<4;i++)
#pragma unroll
        for (int j=0;j<4;j++)
          acc[i][j] = __builtin_amdgcn_mfma_f32_16x16x32_bf16(af[i], bf_[j], acc[i][j], 0, 0, 0);
    }
    __syncthreads();   // also protects smem reuse by epilogue after last iter
  }

  // ---- epilogue: scatter into 32KB LDS window, then dense copy-out ----
  // (R16-verified) window off16 = l_local*8192 + (bb>>2)*512 + (tW+(bb&3))*4 + g
  int dirj = n0 >> 9;
  int u0v  = (n0 & 511) >> 2;   // 32-aligned
  int v0   = u0v >> 4;          // v_start, in {0,2,4,6}
#pragma unroll
  for (int jt=0;jt<4;jt++){
    int j = n0 + wn*64 + jt*16 + lq;          // permuted column
    float bv = bias[j];
    int u = (j >> 2) & 127, g = j & 3;
    int tW = ((u>>4) - v0)*64 + ((u>>2)&3)*16 + (u&3)*4;   // 0..124
#pragma unroll
    for (int i16=0;i16<4;i16++){
#pragma unroll
      for (int r2=0;r2<4;r2++){
        int il = wm*64 + i16*16 + quad*4 + r2;   // local row 0..127
        int bb = il & 63;
        int l_local = il >> 6;                   // == wm
        int off16 = l_local*8192 + (bb>>2)*512 + (tW + (bb&3))*4 + g;
        smem[off16] = f2b(acc[i16][jt][r2] + bv);
      }
    }
  }
  __syncthreads();
  long lbase = m0 >> 6;
#pragma unroll
  for (int seg=0; seg<8; seg++){
    int off16 = (seg*256 + tid) * 8;             // 16B granule, contiguous LDS read
    int l_local = off16 >> 13;
    int grp_local = (off16 >> 9) & 15;
    int rest = off16 & 511;
    long gdst = ((long)(dirj*16 + grp_local) << 21) + ((lbase + l_local) << 11)
              + (long)v0*256 + rest;
    *(u16x8*)(Gp + gdst) = *(const u16x8*)(smem + off16);
  }
}

// layer-1 GEMM (standalone)
__global__ __launch_bounds__(256) void gemm_bt(
    const u16* __restrict__ A, const u16* __restrict__ Bm,
    const float* __restrict__ bias, u16* __restrict__ Gp)
{
  __shared__ __align__(16) u16 smem[16384];
  gemm_body(smem, A, Bm, bias, Gp, (long)blockIdx.x, blockIdx.y);
}

// ---- attention body: e = fbout.catc, softmax over L, proj = catc @ Wih2[:,256:].T ----
// s written TRANSPOSED: sT[l*64 + b]. proj in ORIGINAL column order.
__device__ __forceinline__ void attn_body(
    u16* smem, const u16* __restrict__ y1, const float* __restrict__ catc,
    const float* __restrict__ Wih2f, const float* __restrict__ Wih2b,
    float* __restrict__ sT, float* __restrict__ proj, int b)
{
  float* catv = (float*)smem;            // 256 f
  float* ev   = catv + 256;              // 1024 f
  float* red  = ev + 1024;               // 256 f   (total 6 KB < 32 KB)
  int t = threadIdx.x;
  catv[t] = catc[b*256 + t];
  __syncthreads();
  float evl[4];
#pragma unroll
  for (int r2=0;r2<4;r2++){
    int l = t + r2*256;
    const u16x8* row = (const u16x8*)(y1 + ((long)l*64 + b)*256);
    float acc = 0.f;
    for (int f8=0; f8<32; f8++){
      u16x8 v = row[f8];
#pragma unroll
      for (int k=0;k<8;k++) acc += b2f(v[k]) * catv[f8*8+k];
    }
    ev[l] = acc; evl[r2] = acc;
  }
  float mx = fmaxf(fmaxf(evl[0],evl[1]), fmaxf(evl[2],evl[3]));
  red[t] = mx;
  __syncthreads();
  for (int s=128; s>0; s>>=1){ if (t < s) red[t] = fmaxf(red[t], red[t+s]); __syncthreads(); }
  float m = red[0];
  __syncthreads();
  float sum = 0.f;
#pragma unroll
  for (int r2=0;r2<4;r2++){
    int l = t + r2*256;
    float e = __expf(ev[l] - m);
    ev[l] = e; sum += e;
  }
  red[t] = sum;
  __syncthreads();
  for (int s=128; s>0; s>>=1){ if (t < s) red[t] += red[t+s]; __syncthreads(); }
  float rz = __builtin_amdgcn_rcpf(red[0]);
#pragma unroll
  for (int r2=0;r2<4;r2++){
    int l = t + r2*256;
    sT[(long)l*64 + b] = ev[l] * rz;
  }
#pragma unroll
  for (int r2=0;r2<4;r2++){
    int j = t + r2*256;
    const float* wr = (j < 512) ? (Wih2f + (long)j*512 + 256)
                                : (Wih2b + (long)(j-512)*512 + 256);
    const float4* w4 = (const float4*)wr;
    float acc = 0.f;
#pragma unroll 8
    for (int f4=0; f4<64; f4++){
      float4 v = w4[f4];
      acc += v.x*catv[f4*4+0] + v.y*catv[f4*4+1] + v.z*catv[f4*4+2] + v.w*catv[f4*4+3];
    }
    proj[b*1024 + j] = acc;
  }
}

// ---- fused: attn (blocks 0..63) ∪ layer-2 GEMM (blocks 64..4159) ----
__global__ __launch_bounds__(256) void attn_gemm2(
    const u16* __restrict__ y1, const float* __restrict__ catc,
    const float* __restrict__ Wih2f, const float* __restrict__ Wih2b,
    float* __restrict__ sT, float* __restrict__ proj,
    const u16* __restrict__ Bm, const float* __restrict__ bias,
    u16* __restrict__ Gp)
{
  __shared__ __align__(16) u16 smem[16384];
  int b = blockIdx.x;
  if (b < 64){
    attn_body(smem, y1, catc, Wih2f, Wih2b, sT, proj, b);
  } else {
    int idx = b - 64;
    gemm_body(smem, y1, Bm, bias, Gp, (long)(idx & 511), idx >> 9);
  }
}

// ---------------- persistent BiLSTM layer: 32 WGs x 512 thr (2 dirs x 16 bgroups) ----
// Wave v (0..7): A tiles tau=0..3, tile row m = gate(m&3) of unit v*16+tau+4*(m>>2).
// B cols: ALL 16 cols carry h[batch lq&3] (broadcast) -> D cols are copies.
// D layout (col=lane&15,row=quad*4+r) => acc[tp][r] at the lane's OWN column is
// gate r of its unit U=v*16+4*quad+tp -> 2-deep cndmask select, no cross-lane.
// G'': [grp][l][tid][4] bf16 (grp = dir*16+bg). Running-pointer addressing.
__global__ __launch_bounds__(512, 2) void lstm_layer(
    const u16* __restrict__ G, const float* __restrict__ WhhF, const float* __restrict__ WhhB,
    const float* __restrict__ h0, const float* __restrict__ c0,
    const float* __restrict__ sT, const float* __restrict__ proj,
    u16* __restrict__ Y, float* __restrict__ catOut)
{
  int blk = blockIdx.x;
  int dir = blk >> 4, bg = blk & 15, b0 = bg * 4;
  int tid = threadIdx.x, v = tid >> 6, lane = tid & 63;
  int quad = lane >> 4, lq = lane & 15;
  int b3 = lq & 3, tp = lq >> 2;
  int U = v*16 + 4*quad + tp;                 // this thread's hidden unit
  int batch = b0 + b3;
  const float* Whh = dir ? WhhB : WhhF;

  // [slot][b3*144 + unit]; row stride 144 u16 = 72 words = 8 banks apart per b3
  // -> the 16 distinct b128 read addrs hit each bank <=2x (free).
  __shared__ __align__(16) u16 hbuf[2][576];

  // A-frags: lane holds A[m=lq][k=ks*32+quad*8+j]
  // tile tau row m: gate = m&3, unit = v*16 + tau + 4*(m>>2)
  v8bf Af[4][4];
  {
    int gate = lq & 3;
    int ur = v*16 + 4*(lq>>2);
#pragma unroll
    for (int tau=0;tau<4;tau++){
      const float* wr = Whh + (long)(gate*128 + ur + tau)*128;
#pragma unroll
      for (int ks=0;ks<4;ks++){
        union { u32 w[4]; u16x8 h; } uu;
#pragma unroll
        for (int jj=0;jj<4;jj++){
          float x0 = wr[ks*32 + quad*8 + 2*jj];
          float x1 = wr[ks*32 + quad*8 + 2*jj + 1];
          asm("v_cvt_pk_bf16_f32 %0, %1, %2" : "=v"(uu.w[jj]) : "v"(x0), "v"(x1));
        }
        Af[tau][ks] = __builtin_bit_cast(v8bf, uu.h);
      }
    }
  }

  int wOff = b3*144 + U;                      // own cell
  int rOff[4];
#pragma unroll
  for (int ks=0;ks<4;ks++) rOff[ks] = b3*144 + (ks*4 + quad)*8;

  float cc = c0[dir*8192 + batch*128 + U];
  u16 h0b = f2b(h0[dir*8192 + batch*128 + U]);
  hbuf[0][wOff] = h0b;

  // attention fold (LSTM2): pr[g] = 64*proj[batch, dir*512 + g*128 + U]
  bool att = (proj != nullptr);
  float pr[4];
  if (att){
#pragma unroll
    for (int g=0;g<4;g++)
      pr[g] = 64.0f * proj[(long)batch*1024 + dir*512 + g*128 + U];
  }

  long dl = dir ? -1 : 1;
  long l0 = dir ? 1023 : 0;

  // running pointers (+const step): G prefetch, Y store, sT scalar
  const u16* GbU = G + ((size_t)blk << 21);   // uniform
  int gvo = tid * 4;                          // fixed per-thread, u16 units
  u16x4 gbuf[2];
  gbuf[0] = *(const u16x4*)(GbU + ((size_t)l0 << 11) + gvo);
  gbuf[1] = *(const u16x4*)(GbU + ((size_t)(l0 + dl) << 11) + gvo);
  const u16* gp = GbU + ((size_t)(l0 + 2*dl) << 11) + gvo;  // runs 2 past end: ws-internal
  long gstep = dl << 11;

  u16* yp = Y + l0*16384 + batch*256 + dir*128 + U;
  long ystep = dl * 16384;

  float sv[2] = {0.f, 0.f};
  const float* sp = nullptr;
  long sstep = dl * 64;
  if (att){
    sv[0] = sT[l0*64 + batch];
    sv[1] = sT[(l0 + dl)*64 + batch];
    sp = sT + (l0 + 2*dl)*64 + batch;
  }

  const float NL2E = -1.4426950408889634f;
  const float N2L2E = -2.8853900817779268f;
  v4f zero4 = {0.f, 0.f, 0.f, 0.f};
  __syncthreads();   // full barrier once before the loop (h0 writes + init)

#pragma unroll 2
  for (int it = 0; it < 1024; ++it){
    int slot = it & 1;
    // h fragments FIRST: start LDS latency before the scalar work.
    v8bf bh[4];
#pragma unroll
    for (int ks=0;ks<4;ks++)
      bh[ks] = __builtin_bit_cast(v8bf, *(const u16x8*)(&hbuf[slot][rOff[ks]]));
    // gates for this step (bit-trick unpack: hi half is a bf16 float directly)
    float gc[4];
    {
      u32x2 gw = __builtin_bit_cast(u32x2, gbuf[slot]);
      gc[0] = __builtin_bit_cast(float, gw[0] << 16);
      gc[1] = __builtin_bit_cast(float, gw[0] & 0xFFFF0000u);
      gc[2] = __builtin_bit_cast(float, gw[1] << 16);
      gc[3] = __builtin_bit_cast(float, gw[1] & 0xFFFF0000u);
    }
    gbuf[slot] = *(const u16x4*)gp; gp += gstep;          // prefetch it+2
    float s = 0.f;
    if (att){
      s = sv[slot];
      sv[slot] = *sp; sp += sstep;
    }
    // 4 independent MFMA chains (tau = 0..3)
    v4f a0 = zero4, a1 = zero4, a2 = zero4, a3 = zero4;
    __builtin_amdgcn_s_setprio(1);
#pragma unroll
    for (int ks=0;ks<4;ks++){
      a0 = __builtin_amdgcn_mfma_f32_16x16x32_bf16(Af[0][ks], bh[ks], a0, 0,0,0);
      a1 = __builtin_amdgcn_mfma_f32_16x16x32_bf16(Af[1][ks], bh[ks], a1, 0,0,0);
      a2 = __builtin_amdgcn_mfma_f32_16x16x32_bf16(Af[2][ks], bh[ks], a2, 0,0,0);
      a3 = __builtin_amdgcn_mfma_f32_16x16x32_bf16(Af[3][ks], bh[ks], a3, 0,0,0);
    }
    __builtin_amdgcn_s_setprio(0);

    // select acc[tp] at own column (bit-exact: D cols are broadcast copies)
    float val[4];
#pragma unroll
    for (int r=0;r<4;r++){
      float x01 = (tp & 1) ? a1[r] : a0[r];
      float x23 = (tp & 1) ? a3[r] : a2[r];
      float x   = (tp & 2) ? x23 : x01;
      val[r] = x + gc[r];
    }
    if (att){
#pragma unroll
      for (int r=0;r<4;r++) val[r] = fmaf(s, pr[r], val[r]);
    }

    float i_ = val[0], f_ = val[1], g_ = val[2], o_ = val[3];
    float ef = __builtin_amdgcn_exp2f(f_ * NL2E);
    float ei = __builtin_amdgcn_exp2f(i_ * NL2E);
    float eg = __builtin_amdgcn_exp2f(fminf(g_ * N2L2E, 115.0f));
    float sf = __builtin_amdgcn_rcpf(1.0f + ef);
    float pp = (1.0f - eg) * __builtin_amdgcn_rcpf((1.0f + ei) * (1.0f + eg));
    float c2 = fmaf(cc, sf, pp);
    cc = c2;
    float eo = __builtin_amdgcn_exp2f(o_ * NL2E);
    float ec = __builtin_amdgcn_exp2f(fminf(c2 * N2L2E, 115.0f));
    float hv = (1.0f - ec) * __builtin_amdgcn_rcpf((1.0f + eo) * (1.0f + ec));

    u16 hb = f2b_fast(hv);
    hbuf[slot^1][wOff] = hb;
    *yp = hb; yp += ystep;                    // immediate Y store (same final bytes)
    lds_only_barrier();
  }
  if (catOut)
    catOut[(long)batch*256 + dir*128 + U] = cc;
}

// ---------------- feats = exp(out2 @ Wout.T + bout) (CRF consumes exp domain) ----------------
__global__ __launch_bounds__(256) void featk(const u16* __restrict__ y2,
    const float* __restrict__ Wout, const float* __restrict__ bout, float* __restrict__ feats)
{
  __shared__ float wlds[1280];
  int t = threadIdx.x;
  for (int k=t;k<1280;k+=256) wlds[k] = Wout[k];
  __syncthreads();
  long i = (long)blockIdx.x*256 + t;
  const u16x8* row = (const u16x8*)(y2 + i*256);
  float acc[5] = {0.f,0.f,0.f,0.f,0.f};
  for (int f8=0; f8<32; f8++){
    u16x8 v = row[f8];
#pragma unroll
    for (int k=0;k<8;k++){
      float x = b2f(v[k]);
      int f = f8*8 + k;
#pragma unroll
      for (int c=0;c<5;c++) acc[c] += x * wlds[c*256 + f];
    }
  }
#pragma unroll
  for (int c=0;c<5;c++) feats[i*5 + c] = __expf(acc[c] + bout[c]);
}

// ---------------- CRF forward, exp domain: sc[c] = M + ln E[c] ----------------
// feats arrive pre-exponentiated; renorm every 8 steps (pow-2 scaling is exact,
// growth/step small enough that 8 steps stay far below fp32 range).
__global__ void crf_kernel(const float* __restrict__ feats, const float* __restrict__ masks,
                           const float* __restrict__ trans, float* __restrict__ out)
{
  int b = threadIdx.x;  // 64
  float etr[5][5], tr4[5];
#pragma unroll
  for (int c=0;c<5;c++)
#pragma unroll
    for (int cp=0;cp<5;cp++) etr[c][cp] = __expf(trans[c*5+cp]);  // e^-10000 -> 0
#pragma unroll
  for (int cp=0;cp<5;cp++) tr4[cp] = trans[4*5+cp];   // STOP row
  float E[5] = {0.f, 0.f, 0.f, 1.f, 0.f};             // exp(sc), START=3
  float M = 0.f;
  const float* fpB = feats + (long)b*5120;
  float ftn[5], mtn;
#pragma unroll
  for (int c=0;c<5;c++) ftn[c] = fpB[c];
  mtn = masks[b*1024];
  for (int l=0;l<1024;l++){
    float ft[5]; float mt = mtn;
#pragma unroll
    for (int c=0;c<5;c++) ft[c] = ftn[c];
    if (l < 1023){
      const float* fp = fpB + (l + 1)*5;
#pragma unroll
      for (int c=0;c<5;c++) ftn[c] = fp[c];
      mtn = masks[b*1024 + l + 1];
    }
    float En[5];
#pragma unroll
    for (int c=0;c<5;c++){
      float S = E[0]*etr[c][0];
#pragma unroll
      for (int cp=1;cp<5;cp++) S = fmaf(E[cp], etr[c][cp], S);
      En[c] = S * ft[c];
    }
    bool take = (mt > 0.5f);
#pragma unroll
    for (int c=0;c<5;c++) E[c] = take ? En[c] : E[c];
    if ((l & 7) == 7){
      // exact power-of-2 renorm
      float mx = fmaxf(fmaxf(fmaxf(E[0],E[1]), fmaxf(E[2],E[3])), E[4]);
      int k = (int)((__builtin_bit_cast(unsigned, mx) >> 23) & 0xFFu) - 127;
      float s = __builtin_bit_cast(float, (unsigned)(127 - k) << 23);
#pragma unroll
      for (int c=0;c<5;c++) E[c] *= s;
      M = fmaf((float)k, 0.6931471805599453f, M);
    }
  }
  float Sf = 0.f;
#pragma unroll
  for (int cp=0;cp<5;cp++) Sf = fmaf(E[cp], __expf(tr4[cp]), Sf);
  out[b] = M + __logf(Sf);
}

// ---------------- launcher ----------------
extern "C" void kernel_launch(void* const* d_in, const int* in_sizes, int n_in,
                              void* d_out, int out_size, void* d_ws, size_t ws_size,
                              hipStream_t stream)
{
  const int*   sent  = (const int*)  d_in[0];
  const float* masks = (const float*)d_in[1];
  const float* emb   = (const float*)d_in[2];
  const float* Wih1f = (const float*)d_in[3];
  const float* Whh1f = (const float*)d_in[4];
  const float* bih1f = (const float*)d_in[5];
  const float* bhh1f = (const float*)d_in[6];
  const float* Wih1b = (const float*)d_in[7];
  const float* Whh1b = (const float*)d_in[8];
  const float* bih1b = (const float*)d_in[9];
  const float* bhh1b = (const float*)d_in[10];
  const float* Wih2f = (const float*)d_in[11];
  const float* Whh2f = (const float*)d_in[12];
  const float* bih2f = (const float*)d_in[13];
  const float* bhh2f = (const float*)d_in[14];
  const float* Wih2b = (const float*)d_in[15];
  const float* Whh2b = (const float*)d_in[16];
  const float* bih2b = (const float*)d_in[17];
  const float* bhh2b = (const float*)d_in[18];
  const float* Wout  = (const float*)d_in[19];
  const float* bout  = (const float*)d_in[20];
  const float* trans = (const float*)d_in[21];
  const float* h0    = (const float*)d_in[22];
  const float* c0    = (const float*)d_in[23];
  const float* h02   = (const float*)d_in[24];
  const float* c02   = (const float*)d_in[25];
  float* out = (float*)d_out;

  // workspace layout (aliased: X/y1/y2 share, G per layer shares). ~170.7 MB.
  char* ws = (char*)d_ws;
  u16*   Ybuf  = (u16*)(ws + 0);              // 33,554,432 B: X, then y1, then y2
  u16*   Gbuf  = (u16*)(ws + 33554432);       // 134,217,728 B: G'' per layer (128 MB used)
  u16*   W1cat = (u16*)(ws + 167772160);      // 524,288 B (permuted cols, g fastest)
  u16*   WAcat = (u16*)(ws + 168296448);      // 524,288 B (permuted cols, g fastest)
  float* b1cat = (float*)(ws + 168820736);    // 4,096 B (permuted)
  float* b2cat = (float*)(ws + 168824832);    // 4,096 B (permuted)
  float* catcb = (float*)(ws + 168828928);    // 65,536 B
  float* sbuf  = (float*)(ws + 168894464);    // 262,144 B  (sT[l][64])
  float* projb = (float*)(ws + 169156608);    // 262,144 B (original col order)
  float* featb = (float*)(ws + 169418752);    // 1,310,720 B

  prep_kernel<<<17408, 256, 0, stream>>>(Wih1f, Wih1b, bih1f, bhh1f, bih1b, bhh1b,
                                         Wih2f, Wih2b, bih2f, bhh2f, bih2b, bhh2b,
                                         W1cat, WAcat, b1cat, b2cat, sent, emb, Ybuf);
  gemm_bt<<<dim3(512, 8), 256, 0, stream>>>(Ybuf, W1cat, b1cat, Gbuf);
  lstm_layer<<<32, 512, 0, stream>>>(Gbuf, Whh1f, Whh1b, h0, c0, nullptr, nullptr, Ybuf, catcb);
  attn_gemm2<<<4160, 256, 0, stream>>>(Ybuf, catcb, Wih2f, Wih2b, sbuf, projb,
                                       WAcat, b2cat, Gbuf);
  lstm_layer<<<32, 512, 0, stream>>>(Gbuf, Whh2f, Whh2b, h02, c02, sbuf, projb, Ybuf, nullptr);
  featk<<<256, 256, 0, stream>>>(Ybuf, Wout, bout, featb);
  crf_kernel<<<1, 64, 0, stream>>>(featb, masks, trans, out);
}